// Round 9
// baseline (146.049 us; speedup 1.0000x reference)
//
#include <hip/hip_runtime.h>
#include <math.h>

constexpr int MM = 50;    // members per group
constexpr int DD = 64;    // embedding dim
constexpr int HH = 16;    // attention hidden
constexpr int PH = 8;     // predict hidden
constexpr int WAVES_PER_BLOCK = 4;

// round-to-nearest-even fp32 -> bf16 (as uint16 in low bits)
__device__ __forceinline__ unsigned bf16rne(float f) {
    const unsigned u = __float_as_uint(f);
    return (u + 0x7FFFu + ((u >> 16) & 1u)) >> 16;
}
__device__ __forceinline__ float bf16tof(unsigned short v) {
    return __uint_as_float((unsigned)v << 16);
}

// ============================================================================
// Kernel A: Ubf = bf16(user_table @ W1a)             (nU x 16, pair-packed)
//           Ub  = bf16(user_table)                   (nU x 64)
//           Ib  = item_table[item_inputs] @ W1b + b1 (B x 16) fp32
// ============================================================================
__global__ __launch_bounds__(256) void precompute_kernel(
    const float* __restrict__ user_table,
    const float* __restrict__ item_table,
    const int*   __restrict__ item_inputs,
    const float* __restrict__ att_w1,   // [2D][H] row-major
    const float* __restrict__ att_b1,   // [H]
    unsigned short* __restrict__ Ubf,
    float* __restrict__ Ib,
    unsigned short* __restrict__ Ub,
    int nU, int B, int userBlocks)
{
    const bool isU = (int)blockIdx.x < userBlocks;
    const float4* rp;
    const float*  w1;
    float acc[HH];
    int row = 0;

    if (isU) {
        row = (int)blockIdx.x * 256 + (int)threadIdx.x;
        if (row >= nU) return;
        rp  = (const float4*)(user_table + (size_t)row * DD);
        w1  = att_w1;
        #pragma unroll
        for (int j = 0; j < HH; ++j) acc[j] = 0.0f;
    } else {
        row = ((int)blockIdx.x - userBlocks) * 256 + (int)threadIdx.x;
        if (row >= B) return;
        const int item = item_inputs[row];
        rp  = (const float4*)(item_table + (size_t)item * DD);
        w1  = att_w1 + (size_t)DD * HH;
        #pragma unroll
        for (int j = 0; j < HH; ++j) acc[j] = att_b1[j];
    }

    unsigned brow[DD / 2];

    #pragma unroll 4
    for (int d4 = 0; d4 < DD / 4; ++d4) {
        const float4 x = rp[d4];
        const float* w = w1 + (size_t)(d4 * 4) * HH;       // uniform -> s_load
        #pragma unroll
        for (int j = 0; j < HH; ++j) {
            acc[j] = fmaf(x.x, w[0 * HH + j], acc[j]);
            acc[j] = fmaf(x.y, w[1 * HH + j], acc[j]);
            acc[j] = fmaf(x.z, w[2 * HH + j], acc[j]);
            acc[j] = fmaf(x.w, w[3 * HH + j], acc[j]);
        }
        brow[2 * d4]     = bf16rne(x.x) | (bf16rne(x.y) << 16);
        brow[2 * d4 + 1] = bf16rne(x.z) | (bf16rne(x.w) << 16);
    }

    if (isU) {
        unsigned uw[8];
        #pragma unroll
        for (int w = 0; w < 8; ++w)
            uw[w] = bf16rne(acc[2 * w]) | (bf16rne(acc[2 * w + 1]) << 16);
        uint4* u4 = (uint4*)(Ubf + (size_t)row * HH);
        u4[0] = make_uint4(uw[0], uw[1], uw[2], uw[3]);
        u4[1] = make_uint4(uw[4], uw[5], uw[6], uw[7]);

        uint4* b4 = (uint4*)(Ub + (size_t)row * DD);
        #pragma unroll
        for (int i = 0; i < DD / 8; ++i)
            b4[i] = make_uint4(brow[4 * i], brow[4 * i + 1],
                               brow[4 * i + 2], brow[4 * i + 3]);
    } else {
        float4* o4 = (float4*)(Ib + (size_t)row * HH);
        o4[0] = make_float4(acc[0],  acc[1],  acc[2],  acc[3]);
        o4[1] = make_float4(acc[4],  acc[5],  acc[6],  acc[7]);
        o4[2] = make_float4(acc[8],  acc[9],  acc[10], acc[11]);
        o4[3] = make_float4(acc[12], acc[13], acc[14], acc[15]);
    }
}

// ============================================================================
// Templated per-wave body: NC = number of 8-member chunks (wave-uniform).
// ALL pool-row loads are issued up front (dep only on my_id) so they overlap
// the Ubf score gather + softmax; weights applied afterwards via shfl.
// ============================================================================
template<int NC>
__device__ __forceinline__ void agree_wave(
    const unsigned short* __restrict__ Ubf,
    const float* __restrict__ Ib,
    const unsigned short* __restrict__ Ub,
    const float* __restrict__ att_w2, const float* __restrict__ att_b2,
    const float* __restrict__ pred_w1, const float* __restrict__ pred_b1,
    const float* __restrict__ pred_w2, const float* __restrict__ pred_b2,
    float* __restrict__ out,
    int b, int lane, int my_id, int len, float item_d, float grp_d)
{
    // ---- phase-1 score gather: issue first (consumed first)
    const uint4* up = (const uint4*)(Ubf + ((size_t)(unsigned)my_id * HH));
    const uint4 ua = up[0], ubw = up[1];

    // ---- pool-row loads: issue ALL now (addresses dep only on my_id)
    unsigned short xb[NC * 8];
    #pragma unroll
    for (int k = 0; k < NC * 8; ++k) {
        const int idk = __shfl(my_id, k, 64);               // literal lane
        xb[k] = Ub[(unsigned)(idk * DD + lane)];            // 128B coalesced row
    }

    const float* ib = Ib + (size_t)b * HH;                  // uniform -> s_load
    float score = att_b2[0];
    {
        const unsigned uw[8] = { ua.x, ua.y, ua.z, ua.w,
                                 ubw.x, ubw.y, ubw.z, ubw.w };
        #pragma unroll
        for (int w = 0; w < 8; ++w) {
            const float f0 = __uint_as_float(uw[w] << 16);
            const float f1 = __uint_as_float(uw[w] & 0xFFFF0000u);
            score = fmaf(fmaxf(f0 + ib[2 * w],     0.0f), att_w2[2 * w],     score);
            score = fmaf(fmaxf(f1 + ib[2 * w + 1], 0.0f), att_w2[2 * w + 1], score);
        }
    }

    const bool valid = (lane < MM) && (lane <= len);
    score = valid ? score : -INFINITY;

    float mx = score;
    #pragma unroll
    for (int off = 32; off > 0; off >>= 1) mx = fmaxf(mx, __shfl_xor(mx, off, 64));
    const float e = valid ? __expf(score - mx) : 0.0f;
    float sum = e;
    #pragma unroll
    for (int off = 32; off > 0; off >>= 1) sum += __shfl_xor(sum, off, 64);
    const float wnorm = e / sum;    // 0 for invalid lanes (incl. 50..63)

    // ---- apply softmax weights to the already-in-flight rows
    float g = 0.0f;
    #pragma unroll
    for (int k = 0; k < NC * 8; ++k) {
        const float wk = __shfl(wnorm, k, 64);
        g = fmaf(wk, bf16tof(xb[k]), g);
    }
    g += grp_d;

    // ---- predict MLP: new_e = [g*item, g, item] (192 -> 8 -> 1), lane-per-d
    const float elem = g * item_d;
    float p[PH];
    {
        const float* pa = pred_w1 + (size_t)lane * PH;      // L1-hot
        const float* pb = pred_w1 + (size_t)(DD + lane) * PH;
        const float* pc = pred_w1 + (size_t)(2 * DD + lane) * PH;
        #pragma unroll
        for (int j = 0; j < PH; ++j)
            p[j] = fmaf(elem, pa[j], fmaf(g, pb[j], item_d * pc[j]));
    }
    #pragma unroll
    for (int off = 32; off > 0; off >>= 1) {
        #pragma unroll
        for (int j = 0; j < PH; ++j) p[j] += __shfl_xor(p[j], off, 64);
    }

    if (lane == 0) {
        float acc = pred_b2[0];
        #pragma unroll
        for (int j = 0; j < PH; ++j)
            acc = fmaf(fmaxf(p[j] + pred_b1[j], 0.0f), pred_w2[j], acc);
        out[b] = 1.0f / (1.0f + __expf(-acc));
    }
}

// ============================================================================
// Kernel B: wave-per-row, zero LDS, wave-uniform switch over chunk count.
// ============================================================================
__global__ __launch_bounds__(256) void agree_main(
    const int* __restrict__ group_inputs,
    const int* __restrict__ item_inputs,
    const int* __restrict__ member_ids,
    const int* __restrict__ member_lengths,
    const float* __restrict__ item_table,
    const float* __restrict__ group_table,
    const float* __restrict__ att_w2,
    const float* __restrict__ att_b2,
    const float* __restrict__ pred_w1,
    const float* __restrict__ pred_b1,
    const float* __restrict__ pred_w2,
    const float* __restrict__ pred_b2,
    const unsigned short* __restrict__ Ubf, // [nU][16] bf16
    const float* __restrict__ Ib,           // [B][16], b1 folded
    const unsigned short* __restrict__ Ub,  // [nU][64] bf16
    float* __restrict__ out,
    int B)
{
    const int lane = threadIdx.x & 63;
    const int wv   = threadIdx.x >> 6;
    const int b    = blockIdx.x * WAVES_PER_BLOCK + wv;
    if (b >= B) return;

    const int my_m  = (lane < MM) ? lane : (MM - 1);
    const int my_id = member_ids[b * MM + my_m];            // coalesced
    const int len   = member_lengths[b];                    // uniform
    const int item_idx = item_inputs[b];                    // uniform
    const int gid      = group_inputs[b];                   // uniform

    const float item_d = item_table[(unsigned)(item_idx * DD + lane)];
    const float grp_d  = group_table[(unsigned)(gid * DD + lane)];

    const int mcnt   = (len < MM - 1 ? len : MM - 1) + 1;   // uniform in [1,50]
    const int chunks = (mcnt + 7) >> 3;                     // 1..7, uniform

    switch (chunks) {
    case 1: agree_wave<1>(Ubf, Ib, Ub, att_w2, att_b2, pred_w1, pred_b1,
                          pred_w2, pred_b2, out, b, lane, my_id, len, item_d, grp_d); break;
    case 2: agree_wave<2>(Ubf, Ib, Ub, att_w2, att_b2, pred_w1, pred_b1,
                          pred_w2, pred_b2, out, b, lane, my_id, len, item_d, grp_d); break;
    case 3: agree_wave<3>(Ubf, Ib, Ub, att_w2, att_b2, pred_w1, pred_b1,
                          pred_w2, pred_b2, out, b, lane, my_id, len, item_d, grp_d); break;
    case 4: agree_wave<4>(Ubf, Ib, Ub, att_w2, att_b2, pred_w1, pred_b1,
                          pred_w2, pred_b2, out, b, lane, my_id, len, item_d, grp_d); break;
    case 5: agree_wave<5>(Ubf, Ib, Ub, att_w2, att_b2, pred_w1, pred_b1,
                          pred_w2, pred_b2, out, b, lane, my_id, len, item_d, grp_d); break;
    case 6: agree_wave<6>(Ubf, Ib, Ub, att_w2, att_b2, pred_w1, pred_b1,
                          pred_w2, pred_b2, out, b, lane, my_id, len, item_d, grp_d); break;
    default: agree_wave<7>(Ubf, Ib, Ub, att_w2, att_b2, pred_w1, pred_b1,
                           pred_w2, pred_b2, out, b, lane, my_id, len, item_d, grp_d); break;
    }
}

// ============================================================================
// Fallback if ws too small (self-contained, round-2 structure, full fp32)
// ============================================================================
__global__ __launch_bounds__(256) void agree_fallback(
    const int* __restrict__ group_inputs,
    const int* __restrict__ item_inputs,
    const int* __restrict__ member_ids,
    const int* __restrict__ member_lengths,
    const float* __restrict__ user_table,
    const float* __restrict__ item_table,
    const float* __restrict__ group_table,
    const float* __restrict__ att_w1,
    const float* __restrict__ att_b1,
    const float* __restrict__ att_w2,
    const float* __restrict__ att_b2,
    const float* __restrict__ pred_w1,
    const float* __restrict__ pred_b1,
    const float* __restrict__ pred_w2,
    const float* __restrict__ pred_b2,
    float* __restrict__ out,
    int B)
{
    __shared__ float lds_wt[4][MM];
    __shared__ int   lds_id[4][MM];

    const int lane = threadIdx.x & 63;
    const int wave = threadIdx.x >> 6;
    const int b = blockIdx.x * 4 + wave;
    if (b >= B) return;

    const int my_m = (lane < MM) ? lane : (MM - 1);
    const int my_id = member_ids[b * MM + my_m];
    if (lane < MM) lds_id[wave][lane] = my_id;

    const int item_idx = item_inputs[b];
    const float item_d = item_table[(size_t)item_idx * DD + lane];

    float h[HH];
    {
        const float* w1row = att_w1 + (size_t)(DD + lane) * HH;
        #pragma unroll
        for (int j = 0; j < HH; ++j) h[j] = item_d * w1row[j];
        #pragma unroll
        for (int off = 32; off > 0; off >>= 1) {
            #pragma unroll
            for (int j = 0; j < HH; ++j) h[j] += __shfl_xor(h[j], off, 64);
        }
        #pragma unroll
        for (int j = 0; j < HH; ++j) h[j] += att_b1[j];
    }

    const float* myrow = user_table + (size_t)my_id * DD;
    #pragma unroll 4
    for (int d4 = 0; d4 < DD / 4; ++d4) {
        const float4 x = ((const float4*)myrow)[d4];
        const float* w1d = att_w1 + (size_t)(d4 * 4) * HH;
        #pragma unroll
        for (int j = 0; j < HH; ++j) {
            h[j] = fmaf(x.x, w1d[0 * HH + j], h[j]);
            h[j] = fmaf(x.y, w1d[1 * HH + j], h[j]);
            h[j] = fmaf(x.z, w1d[2 * HH + j], h[j]);
            h[j] = fmaf(x.w, w1d[3 * HH + j], h[j]);
        }
    }

    float score = att_b2[0];
    #pragma unroll
    for (int j = 0; j < HH; ++j) score = fmaf(fmaxf(h[j], 0.0f), att_w2[j], score);

    const int len = member_lengths[b];
    const bool valid = (lane < MM) && (lane <= len);
    score = valid ? score : -INFINITY;

    float mx = score;
    #pragma unroll
    for (int off = 32; off > 0; off >>= 1) mx = fmaxf(mx, __shfl_xor(mx, off, 64));
    float e = valid ? __expf(score - mx) : 0.0f;
    float sum = e;
    #pragma unroll
    for (int off = 32; off > 0; off >>= 1) sum += __shfl_xor(sum, off, 64);
    if (lane < MM) lds_wt[wave][lane] = e / sum;
    __builtin_amdgcn_s_waitcnt(0);

    const int mcnt = (len < MM - 1 ? len : MM - 1) + 1;
    float g = 0.0f;
    #pragma unroll 2
    for (int m = 0; m < mcnt; ++m) {
        g = fmaf(lds_wt[wave][m],
                 user_table[(size_t)lds_id[wave][m] * DD + lane], g);
    }
    const int gid = group_inputs[b];
    g += group_table[(size_t)gid * DD + lane];

    const float elem = g * item_d;
    float p[PH];
    {
        const float* pa = pred_w1 + (size_t)lane * PH;
        const float* pb = pred_w1 + (size_t)(DD + lane) * PH;
        const float* pc = pred_w1 + (size_t)(2 * DD + lane) * PH;
        #pragma unroll
        for (int j = 0; j < PH; ++j)
            p[j] = fmaf(elem, pa[j], fmaf(g, pb[j], item_d * pc[j]));
    }
    #pragma unroll
    for (int off = 32; off > 0; off >>= 1) {
        #pragma unroll
        for (int j = 0; j < PH; ++j) p[j] += __shfl_xor(p[j], off, 64);
    }

    if (lane == 0) {
        float acc = pred_b2[0];
        #pragma unroll
        for (int j = 0; j < PH; ++j)
            acc = fmaf(fmaxf(p[j] + pred_b1[j], 0.0f), pred_w2[j], acc);
        out[b] = 1.0f / (1.0f + __expf(-acc));
    }
}

extern "C" void kernel_launch(void* const* d_in, const int* in_sizes, int n_in,
                              void* d_out, int out_size, void* d_ws, size_t ws_size,
                              hipStream_t stream) {
    const int*   group_inputs   = (const int*)d_in[0];
    const int*   item_inputs    = (const int*)d_in[1];
    const int*   member_ids     = (const int*)d_in[2];
    const int*   member_lengths = (const int*)d_in[3];
    const float* user_table     = (const float*)d_in[4];
    const float* item_table     = (const float*)d_in[5];
    const float* group_table    = (const float*)d_in[6];
    const float* att_w1         = (const float*)d_in[7];
    const float* att_b1         = (const float*)d_in[8];
    const float* att_w2         = (const float*)d_in[9];
    const float* att_b2         = (const float*)d_in[10];
    const float* pred_w1        = (const float*)d_in[11];
    const float* pred_b1        = (const float*)d_in[12];
    const float* pred_w2        = (const float*)d_in[13];
    const float* pred_b2        = (const float*)d_in[14];
    float* out = (float*)d_out;

    const int B  = in_sizes[0];
    const int nU = in_sizes[4] / DD;
    // ws layout: Ubf (nU*16 bf16) | Ib (B*16 f32) | Ub (nU*64 bf16)
    const size_t need = (size_t)nU * HH * sizeof(unsigned short)
                      + (size_t)B  * HH * sizeof(float)
                      + (size_t)nU * DD * sizeof(unsigned short);
    const int blocks = (B + WAVES_PER_BLOCK - 1) / WAVES_PER_BLOCK;

    if (ws_size >= need) {
        unsigned short* Ubf = (unsigned short*)d_ws;
        float* Ib = (float*)(Ubf + (size_t)nU * HH);
        unsigned short* Ub = (unsigned short*)(Ib + (size_t)B * HH);
        const int userBlocks = (nU + 255) / 256;
        const int itemBlocks = (B + 255) / 256;
        precompute_kernel<<<userBlocks + itemBlocks, 256, 0, stream>>>(
            user_table, item_table, item_inputs, att_w1, att_b1,
            Ubf, Ib, Ub, nU, B, userBlocks);
        agree_main<<<blocks, 256, 0, stream>>>(
            group_inputs, item_inputs, member_ids, member_lengths,
            item_table, group_table,
            att_w2, att_b2, pred_w1, pred_b1, pred_w2, pred_b2,
            Ubf, Ib, Ub, out, B);
    } else {
        agree_fallback<<<blocks, 256, 0, stream>>>(
            group_inputs, item_inputs, member_ids, member_lengths,
            user_table, item_table, group_table,
            att_w1, att_b1, att_w2, att_b2,
            pred_w1, pred_b1, pred_w2, pred_b2,
            out, B);
    }
}

// Round 10
// 145.302 us; speedup vs baseline: 1.0051x; 1.0051x over previous
//
#include <hip/hip_runtime.h>
#include <math.h>

constexpr int MM = 50;    // members per group
constexpr int DD = 64;    // embedding dim
constexpr int HH = 16;    // attention hidden
constexpr int PH = 8;     // predict hidden
constexpr int WAVES_PER_BLOCK = 4;
constexpr int SLOTS = 56; // 7 chunks x 8, zero-padded past member 49
constexpr int PRE = 16;   // pool rows prefetched before softmax (2 chunks)

// round-to-nearest-even fp32 -> bf16 (as uint16 in low bits)
__device__ __forceinline__ unsigned bf16rne(float f) {
    const unsigned u = __float_as_uint(f);
    return (u + 0x7FFFu + ((u >> 16) & 1u)) >> 16;
}
__device__ __forceinline__ float bf16tof(unsigned short v) {
    return __uint_as_float((unsigned)v << 16);
}

// ============================================================================
// Kernel A: Ubf = bf16(user_table @ W1a)             (nU x 16, pair-packed)
//           Ub  = bf16(user_table)                   (nU x 64)
//           Ib  = item_table[item_inputs] @ W1b + b1 (B x 16) fp32
// ============================================================================
__global__ __launch_bounds__(256) void precompute_kernel(
    const float* __restrict__ user_table,
    const float* __restrict__ item_table,
    const int*   __restrict__ item_inputs,
    const float* __restrict__ att_w1,   // [2D][H] row-major
    const float* __restrict__ att_b1,   // [H]
    unsigned short* __restrict__ Ubf,
    float* __restrict__ Ib,
    unsigned short* __restrict__ Ub,
    int nU, int B, int userBlocks)
{
    const bool isU = (int)blockIdx.x < userBlocks;
    const float4* rp;
    const float*  w1;
    float acc[HH];
    int row = 0;

    if (isU) {
        row = (int)blockIdx.x * 256 + (int)threadIdx.x;
        if (row >= nU) return;
        rp  = (const float4*)(user_table + (size_t)row * DD);
        w1  = att_w1;
        #pragma unroll
        for (int j = 0; j < HH; ++j) acc[j] = 0.0f;
    } else {
        row = ((int)blockIdx.x - userBlocks) * 256 + (int)threadIdx.x;
        if (row >= B) return;
        const int item = item_inputs[row];
        rp  = (const float4*)(item_table + (size_t)item * DD);
        w1  = att_w1 + (size_t)DD * HH;
        #pragma unroll
        for (int j = 0; j < HH; ++j) acc[j] = att_b1[j];
    }

    unsigned brow[DD / 2];

    #pragma unroll 4
    for (int d4 = 0; d4 < DD / 4; ++d4) {
        const float4 x = rp[d4];
        const float* w = w1 + (size_t)(d4 * 4) * HH;       // uniform -> s_load
        #pragma unroll
        for (int j = 0; j < HH; ++j) {
            acc[j] = fmaf(x.x, w[0 * HH + j], acc[j]);
            acc[j] = fmaf(x.y, w[1 * HH + j], acc[j]);
            acc[j] = fmaf(x.z, w[2 * HH + j], acc[j]);
            acc[j] = fmaf(x.w, w[3 * HH + j], acc[j]);
        }
        brow[2 * d4]     = bf16rne(x.x) | (bf16rne(x.y) << 16);
        brow[2 * d4 + 1] = bf16rne(x.z) | (bf16rne(x.w) << 16);
    }

    if (isU) {
        unsigned uw[8];
        #pragma unroll
        for (int w = 0; w < 8; ++w)
            uw[w] = bf16rne(acc[2 * w]) | (bf16rne(acc[2 * w + 1]) << 16);
        uint4* u4 = (uint4*)(Ubf + (size_t)row * HH);
        u4[0] = make_uint4(uw[0], uw[1], uw[2], uw[3]);
        u4[1] = make_uint4(uw[4], uw[5], uw[6], uw[7]);

        uint4* b4 = (uint4*)(Ub + (size_t)row * DD);
        #pragma unroll
        for (int i = 0; i < DD / 8; ++i)
            b4[i] = make_uint4(brow[4 * i], brow[4 * i + 1],
                               brow[4 * i + 2], brow[4 * i + 3]);
    } else {
        float4* o4 = (float4*)(Ib + (size_t)row * HH);
        o4[0] = make_float4(acc[0],  acc[1],  acc[2],  acc[3]);
        o4[1] = make_float4(acc[4],  acc[5],  acc[6],  acc[7]);
        o4[2] = make_float4(acc[8],  acc[9],  acc[10], acc[11]);
        o4[3] = make_float4(acc[12], acc[13], acc[14], acc[15]);
    }
}

// ============================================================================
// Kernel B: wave-per-row (R8 structure) + bounded prefetch of the first 16
// pool rows before softmax. Remaining chunks via LDS pairs after softmax.
// ============================================================================
__global__ __launch_bounds__(256) void agree_main(
    const int* __restrict__ group_inputs,
    const int* __restrict__ item_inputs,
    const int* __restrict__ member_ids,
    const int* __restrict__ member_lengths,
    const float* __restrict__ item_table,
    const float* __restrict__ group_table,
    const float* __restrict__ att_w2,   // [H]
    const float* __restrict__ att_b2,   // [1]
    const float* __restrict__ pred_w1,  // [3D][8]
    const float* __restrict__ pred_b1,  // [8]
    const float* __restrict__ pred_w2,  // [8]
    const float* __restrict__ pred_b2,  // [1]
    const unsigned short* __restrict__ Ubf, // [nU][16] bf16 pair-packed
    const float* __restrict__ Ib,       // [B][16], b1 folded
    const unsigned short* __restrict__ Ub, // [nU][64] bf16
    float* __restrict__ out,
    int B)
{
    __shared__ float2 pairs[WAVES_PER_BLOCK][SLOTS]; // (wnorm, id bits), 1792 B

    const int lane = threadIdx.x & 63;
    const int wv   = threadIdx.x >> 6;
    const int b    = blockIdx.x * WAVES_PER_BLOCK + wv;
    if (b >= B) return;

    const int my_m  = (lane < MM) ? lane : (MM - 1);
    const int my_id = member_ids[b * MM + my_m];            // coalesced
    const int len   = member_lengths[b];                    // uniform
    const int item_idx = item_inputs[b];                    // uniform
    const int gid      = group_inputs[b];                   // uniform

    // issue post-softmax rows early so they're in flight during phase 1
    const float item_d = item_table[(unsigned)(item_idx * DD + lane)];
    const float grp_d  = group_table[(unsigned)(gid * DD + lane)];

    // ---- phase-1 score gather (consumed first — issue first)
    const uint4* up = (const uint4*)(Ubf + ((size_t)(unsigned)my_id * HH));
    const uint4 ua = up[0], ubw = up[1];

    // ---- prefetch first PRE pool rows (addresses dep only on my_id);
    // literal-lane shfl -> v_readlane, saddr-form loads, all in flight now
    unsigned short xpre[PRE];
    #pragma unroll
    for (int k = 0; k < PRE; ++k) {
        const int idk = __shfl(my_id, k, 64);
        xpre[k] = Ub[(unsigned)(idk * DD + lane)];          // 128B coalesced row
    }

    const float* ib = Ib + (size_t)b * HH;                  // uniform -> s_load
    float score = att_b2[0];
    {
        const unsigned uw[8] = { ua.x, ua.y, ua.z, ua.w,
                                 ubw.x, ubw.y, ubw.z, ubw.w };
        #pragma unroll
        for (int w = 0; w < 8; ++w) {
            const float f0 = __uint_as_float(uw[w] << 16);          // dim 2w
            const float f1 = __uint_as_float(uw[w] & 0xFFFF0000u);  // dim 2w+1
            score = fmaf(fmaxf(f0 + ib[2 * w],     0.0f), att_w2[2 * w],     score);
            score = fmaf(fmaxf(f1 + ib[2 * w + 1], 0.0f), att_w2[2 * w + 1], score);
        }
    }

    const bool valid = (lane < MM) && (lane <= len);
    score = valid ? score : -INFINITY;

    // softmax over members (member 0 always valid)
    float mx = score;
    #pragma unroll
    for (int off = 32; off > 0; off >>= 1) mx = fmaxf(mx, __shfl_xor(mx, off, 64));
    const float e = valid ? __expf(score - mx) : 0.0f;
    float sum = e;
    #pragma unroll
    for (int off = 32; off > 0; off >>= 1) sum += __shfl_xor(sum, off, 64);
    const float wnorm = e / sum;    // 0 for invalid lanes (incl. 50..63)

    // stash (wnorm, id) pairs for chunks >= 2; slots 50..55 get wnorm=0
    if (lane < SLOTS) pairs[wv][lane] = make_float2(wnorm, __int_as_float(my_id));
    __builtin_amdgcn_s_waitcnt(0);  // drain own-wave LDS writes (no barrier)

    // ---- consume the prefetched rows (wnorm=0 kills members beyond len)
    float g = 0.0f;
    #pragma unroll
    for (int k = 0; k < PRE; ++k) {
        const float wk = __shfl(wnorm, k, 64);              // v_readlane
        g = fmaf(wk, bf16tof(xpre[k]), g);
    }

    // ---- remaining chunks (avg ~1.3), R8 LDS-pair loop
    const int mcnt   = (len < MM - 1 ? len : MM - 1) + 1;   // uniform in [1,50]
    const int chunks = (mcnt + 7) >> 3;                     // 1..7, uniform
    for (int c = PRE / 8; c < chunks; ++c) {
        float2 q[8];
        #pragma unroll
        for (int k = 0; k < 8; ++k) q[k] = pairs[wv][c * 8 + k]; // broadcast reads
        unsigned short xb[8];
        #pragma unroll
        for (int k = 0; k < 8; ++k) {
            const unsigned idx = (unsigned)(__float_as_int(q[k].y) * DD + lane);
            xb[k] = Ub[idx];                                // 128B coalesced bf16 row
        }
        #pragma unroll
        for (int k = 0; k < 8; ++k)
            g = fmaf(q[k].x, bf16tof(xb[k]), g);
    }
    g += grp_d;

    // ---- predict MLP: new_e = [g*item, g, item] (192 -> 8 -> 1), lane-per-d
    const float elem = g * item_d;
    float p[PH];
    {
        const float* pa = pred_w1 + (size_t)lane * PH;      // L1-hot
        const float* pb = pred_w1 + (size_t)(DD + lane) * PH;
        const float* pc = pred_w1 + (size_t)(2 * DD + lane) * PH;
        #pragma unroll
        for (int j = 0; j < PH; ++j)
            p[j] = fmaf(elem, pa[j], fmaf(g, pb[j], item_d * pc[j]));
    }
    #pragma unroll
    for (int off = 32; off > 0; off >>= 1) {
        #pragma unroll
        for (int j = 0; j < PH; ++j) p[j] += __shfl_xor(p[j], off, 64);
    }

    if (lane == 0) {
        float acc = pred_b2[0];
        #pragma unroll
        for (int j = 0; j < PH; ++j)
            acc = fmaf(fmaxf(p[j] + pred_b1[j], 0.0f), pred_w2[j], acc);
        out[b] = 1.0f / (1.0f + __expf(-acc));
    }
}

// ============================================================================
// Fallback if ws too small (self-contained, round-2 structure, full fp32)
// ============================================================================
__global__ __launch_bounds__(256) void agree_fallback(
    const int* __restrict__ group_inputs,
    const int* __restrict__ item_inputs,
    const int* __restrict__ member_ids,
    const int* __restrict__ member_lengths,
    const float* __restrict__ user_table,
    const float* __restrict__ item_table,
    const float* __restrict__ group_table,
    const float* __restrict__ att_w1,
    const float* __restrict__ att_b1,
    const float* __restrict__ att_w2,
    const float* __restrict__ att_b2,
    const float* __restrict__ pred_w1,
    const float* __restrict__ pred_b1,
    const float* __restrict__ pred_w2,
    const float* __restrict__ pred_b2,
    float* __restrict__ out,
    int B)
{
    __shared__ float lds_wt[4][MM];
    __shared__ int   lds_id[4][MM];

    const int lane = threadIdx.x & 63;
    const int wave = threadIdx.x >> 6;
    const int b = blockIdx.x * 4 + wave;
    if (b >= B) return;

    const int my_m = (lane < MM) ? lane : (MM - 1);
    const int my_id = member_ids[b * MM + my_m];
    if (lane < MM) lds_id[wave][lane] = my_id;

    const int item_idx = item_inputs[b];
    const float item_d = item_table[(size_t)item_idx * DD + lane];

    float h[HH];
    {
        const float* w1row = att_w1 + (size_t)(DD + lane) * HH;
        #pragma unroll
        for (int j = 0; j < HH; ++j) h[j] = item_d * w1row[j];
        #pragma unroll
        for (int off = 32; off > 0; off >>= 1) {
            #pragma unroll
            for (int j = 0; j < HH; ++j) h[j] += __shfl_xor(h[j], off, 64);
        }
        #pragma unroll
        for (int j = 0; j < HH; ++j) h[j] += att_b1[j];
    }

    const float* myrow = user_table + (size_t)my_id * DD;
    #pragma unroll 4
    for (int d4 = 0; d4 < DD / 4; ++d4) {
        const float4 x = ((const float4*)myrow)[d4];
        const float* w1d = att_w1 + (size_t)(d4 * 4) * HH;
        #pragma unroll
        for (int j = 0; j < HH; ++j) {
            h[j] = fmaf(x.x, w1d[0 * HH + j], h[j]);
            h[j] = fmaf(x.y, w1d[1 * HH + j], h[j]);
            h[j] = fmaf(x.z, w1d[2 * HH + j], h[j]);
            h[j] = fmaf(x.w, w1d[3 * HH + j], h[j]);
        }
    }

    float score = att_b2[0];
    #pragma unroll
    for (int j = 0; j < HH; ++j) score = fmaf(fmaxf(h[j], 0.0f), att_w2[j], score);

    const int len = member_lengths[b];
    const bool valid = (lane < MM) && (lane <= len);
    score = valid ? score : -INFINITY;

    float mx = score;
    #pragma unroll
    for (int off = 32; off > 0; off >>= 1) mx = fmaxf(mx, __shfl_xor(mx, off, 64));
    float e = valid ? __expf(score - mx) : 0.0f;
    float sum = e;
    #pragma unroll
    for (int off = 32; off > 0; off >>= 1) sum += __shfl_xor(sum, off, 64);
    if (lane < MM) lds_wt[wave][lane] = e / sum;
    __builtin_amdgcn_s_waitcnt(0);

    const int mcnt = (len < MM - 1 ? len : MM - 1) + 1;
    float g = 0.0f;
    #pragma unroll 2
    for (int m = 0; m < mcnt; ++m) {
        g = fmaf(lds_wt[wave][m],
                 user_table[(size_t)lds_id[wave][m] * DD + lane], g);
    }
    const int gid = group_inputs[b];
    g += group_table[(size_t)gid * DD + lane];

    const float elem = g * item_d;
    float p[PH];
    {
        const float* pa = pred_w1 + (size_t)lane * PH;
        const float* pb = pred_w1 + (size_t)(DD + lane) * PH;
        const float* pc = pred_w1 + (size_t)(2 * DD + lane) * PH;
        #pragma unroll
        for (int j = 0; j < PH; ++j)
            p[j] = fmaf(elem, pa[j], fmaf(g, pb[j], item_d * pc[j]));
    }
    #pragma unroll
    for (int off = 32; off > 0; off >>= 1) {
        #pragma unroll
        for (int j = 0; j < PH; ++j) p[j] += __shfl_xor(p[j], off, 64);
    }

    if (lane == 0) {
        float acc = pred_b2[0];
        #pragma unroll
        for (int j = 0; j < PH; ++j)
            acc = fmaf(fmaxf(p[j] + pred_b1[j], 0.0f), pred_w2[j], acc);
        out[b] = 1.0f / (1.0f + __expf(-acc));
    }
}

extern "C" void kernel_launch(void* const* d_in, const int* in_sizes, int n_in,
                              void* d_out, int out_size, void* d_ws, size_t ws_size,
                              hipStream_t stream) {
    const int*   group_inputs   = (const int*)d_in[0];
    const int*   item_inputs    = (const int*)d_in[1];
    const int*   member_ids     = (const int*)d_in[2];
    const int*   member_lengths = (const int*)d_in[3];
    const float* user_table     = (const float*)d_in[4];
    const float* item_table     = (const float*)d_in[5];
    const float* group_table    = (const float*)d_in[6];
    const float* att_w1         = (const float*)d_in[7];
    const float* att_b1         = (const float*)d_in[8];
    const float* att_w2         = (const float*)d_in[9];
    const float* att_b2         = (const float*)d_in[10];
    const float* pred_w1        = (const float*)d_in[11];
    const float* pred_b1        = (const float*)d_in[12];
    const float* pred_w2        = (const float*)d_in[13];
    const float* pred_b2        = (const float*)d_in[14];
    float* out = (float*)d_out;

    const int B  = in_sizes[0];
    const int nU = in_sizes[4] / DD;
    // ws layout: Ubf (nU*16 bf16) | Ib (B*16 f32) | Ub (nU*64 bf16)
    const size_t need = (size_t)nU * HH * sizeof(unsigned short)
                      + (size_t)B  * HH * sizeof(float)
                      + (size_t)nU * DD * sizeof(unsigned short);
    const int blocks = (B + WAVES_PER_BLOCK - 1) / WAVES_PER_BLOCK;

    if (ws_size >= need) {
        unsigned short* Ubf = (unsigned short*)d_ws;
        float* Ib = (float*)(Ubf + (size_t)nU * HH);
        unsigned short* Ub = (unsigned short*)(Ib + (size_t)B * HH);
        const int userBlocks = (nU + 255) / 256;
        const int itemBlocks = (B + 255) / 256;
        precompute_kernel<<<userBlocks + itemBlocks, 256, 0, stream>>>(
            user_table, item_table, item_inputs, att_w1, att_b1,
            Ubf, Ib, Ub, nU, B, userBlocks);
        agree_main<<<blocks, 256, 0, stream>>>(
            group_inputs, item_inputs, member_ids, member_lengths,
            item_table, group_table,
            att_w2, att_b2, pred_w1, pred_b1, pred_w2, pred_b2,
            Ubf, Ib, Ub, out, B);
    } else {
        agree_fallback<<<blocks, 256, 0, stream>>>(
            group_inputs, item_inputs, member_ids, member_lengths,
            user_table, item_table, group_table,
            att_w1, att_b1, att_w2, att_b2,
            pred_w1, pred_b1, pred_w2, pred_b2,
            out, B);
    }
}